// Round 4
// baseline (54.649 us; speedup 1.0000x reference)
//
#include <hip/hip_runtime.h>
#include <math.h>

#define Bsz 32
#define Cc  16
#define Hh  64
#define Ww  64
#define HO  62
#define WO  62
#define OD  64
#define ND  144           // d = c*9 + di*3 + dj
#define NCHUNK 36         // K = 1152 = 36 chunks of 32 (4 d's per chunk)
#define BSKEW 520         // ushorts per d-block in skewed B (1040 B)
#define BSM_U16 77824     // 19*512*8 ushorts = 155,648 B LDS image

using short8 = __attribute__((ext_vector_type(8))) short;
using f32x4  = __attribute__((ext_vector_type(4))) float;

__device__ __forceinline__ unsigned short f2bf(float f) {
    union { float f; unsigned u; } v; v.f = f;
    unsigned r = v.u + 0x7fff + ((v.u >> 16) & 1);
    return (unsigned short)(r >> 16);
}
__device__ __forceinline__ float bf2f(unsigned short h) {
    union { unsigned u; float f; } v; v.u = ((unsigned)h) << 16; return v.f;
}

__device__ __forceinline__ uint4 feat_pack(float xv) {
    float xi = (xv + 3.0f) * 1.5f;
    float fi = floorf(xi);
    int   ii = (int)fi;
    float u  = xi - fi;
    float u2 = u * u, u3 = u2 * u;
    float P0 = u3 * (1.0f / 6.0f);
    float P1 = (1.0f + 3.0f * u + 3.0f * u2 - 3.0f * u3) * (1.0f / 6.0f);
    float P2 = (4.0f - 6.0f * u2 + 3.0f * u3) * (1.0f / 6.0f);
    float om = 1.0f - u;
    float P3 = om * om * om * (1.0f / 6.0f);
    bool ok = (ii >= 0) && (ii <= 8);
    float bas[6];
    #pragma unroll
    for (int n = 0; n < 6; ++n) {
        int t = ii - n;
        float v = (t == 0) ? P0 : (t == 1) ? P1 : (t == 2) ? P2 : (t == 3) ? P3 : 0.0f;
        bas[n] = ok ? v : 0.0f;
    }
    float s = xv / (1.0f + __expf(-xv));
    unsigned short sh = f2bf(s);
    unsigned short sl = f2bf(s - bf2f(sh));
    uint4 pk;
    pk.x = (unsigned)f2bf(bas[0]) | ((unsigned)f2bf(bas[1]) << 16);
    pk.y = (unsigned)f2bf(bas[2]) | ((unsigned)f2bf(bas[3]) << 16);
    pk.z = (unsigned)f2bf(bas[4]) | ((unsigned)f2bf(bas[5]) << 16);
    pk.w = (unsigned)sh | ((unsigned)sl << 16);
    return pk;
}

// ---- kernel 1 (fused): blocks <1024 compute features (float4-vectorized);
//      blocks >=1024 pack the skewed bf16 weight image ----
__global__ __launch_bounds__(256) void kan_feat(const float* __restrict__ x,
                                                const float* __restrict__ coef,
                                                const float* __restrict__ sbase,
                                                const float* __restrict__ ssp,
                                                uint4* __restrict__ fg,
                                                unsigned short* __restrict__ wps) {
    const int bid = blockIdx.x, tid = threadIdx.x;
    if (bid < 1024) {
        #pragma unroll
        for (int p = 0; p < 2; ++p) {
            int e0 = bid * 2048 + p * 1024 + tid * 4;
            float4 xv = *(const float4*)&x[e0];
            fg[e0 + 0] = feat_pack(xv.x);
            fg[e0 + 1] = feat_pack(xv.y);
            fg[e0 + 2] = feat_pack(xv.z);
            fg[e0 + 3] = feat_pack(xv.w);
        }
    } else {
        int g = (bid - 1024) * 256 + tid;      // uint4 index, < 9728
        if (g >= BSM_U16 / 8) return;
        int p8   = g * 8;
        int dd   = p8 / BSKEW;
        int rem8 = (p8 - dd * BSKEW) >> 3;     // 0..64 (o index or pad)
        unsigned short v8[8];
        #pragma unroll
        for (int n = 0; n < 8; ++n) v8[n] = 0;
        if (dd < ND && rem8 < 64) {
            int o = rem8;
            float sspv = ssp[dd * OD + o];
            #pragma unroll
            for (int n = 0; n < 6; ++n) v8[n] = f2bf(coef[(dd * OD + o) * 6 + n] * sspv);
            unsigned short sb = f2bf(sbase[dd * OD + o]);
            v8[6] = sb; v8[7] = sb;            // silu hi + lo both hit scale_base
        }
        uint4 pk;
        pk.x = (unsigned)v8[0] | ((unsigned)v8[1] << 16);
        pk.y = (unsigned)v8[2] | ((unsigned)v8[3] << 16);
        pk.z = (unsigned)v8[4] | ((unsigned)v8[5] << 16);
        pk.w = (unsigned)v8[6] | ((unsigned)v8[7] << 16);
        *(uint4*)&wps[p8] = pk;
    }
}

// ---- kernel 2: GEMM, B in LDS, wave = one output row, 3-deep A / 2-deep B pipeline ----
__global__ __launch_bounds__(512) void kan_gemm(const uint4* __restrict__ fg,
                                                const unsigned short* __restrict__ wps,
                                                float* __restrict__ out) {
    __shared__ unsigned short bsm[BSM_U16];   // 155,648 B

    const int tid  = threadIdx.x;
    const int bb   = blockIdx.x >> 3;
    const int wid  = tid >> 6;
    const int h    = (blockIdx.x & 7) * 8 + wid;
    const int lane = tid & 63;
    const int l15  = lane & 15;
    const int ks   = lane >> 4;
    const bool alive = (h < HO);

    {   // stage B (global -> LDS)
        const uint4* src = (const uint4*)wps;
        uint4* dst = (uint4*)bsm;
        #pragma unroll
        for (int it = 0; it < 19; ++it) dst[it * 512 + tid] = src[it * 512 + tid];
    }
    __syncthreads();

    f32x4 acc[4][4];
    #pragma unroll
    for (int rt = 0; rt < 4; ++rt)
        #pragma unroll
        for (int ct = 0; ct < 4; ++ct) acc[rt][ct] = (f32x4){0.f, 0.f, 0.f, 0.f};

    if (alive) {
        const unsigned short* bbase = bsm + ks * BSKEW + l15 * 8;

        auto loadA = [&](int cb, short8* A) {
            int dd  = cb * 4 + ks;
            int c   = (dd * 57) >> 9;         // dd/9
            int rem = dd - c * 9;
            int di  = (rem * 11) >> 5;        // rem/3
            int dj  = rem - di * 3;
            const short8* ap = (const short8*)fg + ((((bb * Cc + c) << 6) + h + di) << 6) + l15 + dj;
            A[0] = ap[0]; A[1] = ap[16]; A[2] = ap[32]; A[3] = ap[48];
        };
        auto loadB = [&](int cb, short8* Bf) {
            const short8* bp = (const short8*)(bbase + cb * 4 * BSKEW);
            Bf[0] = bp[0]; Bf[1] = bp[16]; Bf[2] = bp[32]; Bf[3] = bp[48];
        };
        auto mfmas = [&](short8* Ax, short8* Bx) {
            #pragma unroll
            for (int rt = 0; rt < 4; ++rt)
                #pragma unroll
                for (int ct = 0; ct < 4; ++ct)
                    acc[rt][ct] = __builtin_amdgcn_mfma_f32_16x16x32_bf16(Ax[rt], Bx[ct], acc[rt][ct], 0, 0, 0);
        };

        short8 A0[4], A1[4], A2[4], B0[4], B1[4];
        loadA(0, A0); loadA(1, A1); loadA(2, A2);
        loadB(0, B0); loadB(1, B1);

        for (int cb = 0; cb < NCHUNK; cb += 6) {
            mfmas(A0, B0);
            if (cb + 3 < NCHUNK) loadA(cb + 3, A0);
            if (cb + 2 < NCHUNK) loadB(cb + 2, B0);
            mfmas(A1, B1);
            if (cb + 4 < NCHUNK) loadA(cb + 4, A1);
            if (cb + 3 < NCHUNK) loadB(cb + 3, B1);
            mfmas(A2, B0);
            if (cb + 5 < NCHUNK) loadA(cb + 5, A2);
            if (cb + 4 < NCHUNK) loadB(cb + 4, B0);
            mfmas(A0, B1);
            if (cb + 6 < NCHUNK) loadA(cb + 6, A0);
            if (cb + 5 < NCHUNK) loadB(cb + 5, B1);
            mfmas(A1, B0);
            if (cb + 7 < NCHUNK) loadA(cb + 7, A1);
            if (cb + 6 < NCHUNK) loadB(cb + 6, B0);
            mfmas(A2, B1);
            if (cb + 8 < NCHUNK) loadA(cb + 8, A2);
            if (cb + 7 < NCHUNK) loadB(cb + 7, B1);
        }
    }

    // epilogue: reuse B-LDS as per-wave transpose scratch
    __syncthreads();
    if (alive) {
        float* sc = (float*)bsm + wid * (OD * 68);
        #pragma unroll
        for (int rt = 0; rt < 4; ++rt)
            #pragma unroll
            for (int ct = 0; ct < 4; ++ct)
                *(f32x4*)&sc[(ct * 16 + l15) * 68 + rt * 16 + ks * 4] = acc[rt][ct];

        const int jh = lane >> 5;          // 0..1
        const int r  = lane & 31;          // 0..31
        #pragma unroll 8
        for (int it = 0; it < 32; ++it) {
            int j = it * 2 + jh;
            if (r < 31) {
                float2 v = *(float2*)&sc[j * 68 + r * 2];
                *(float2*)&out[((bb * OD + j) * HO + h) * WO + r * 2] = v;
            }
        }
    }
}

// =================== fallback path (round-2 kernels, no large ws) ===================
#define FW 68
__global__ __launch_bounds__(256) void kan_prep(const float* __restrict__ coef,
                                                const float* __restrict__ sbase,
                                                const float* __restrict__ ssp,
                                                unsigned short* __restrict__ wp) {
    int idx = blockIdx.x * 256 + threadIdx.x;
    if (idx >= ND * OD * 8) return;
    int n = idx & 7, o = (idx >> 3) & 63, d = idx >> 9;
    float v = (n < 6) ? coef[(d * OD + o) * 6 + n] * ssp[d * OD + o] : sbase[d * OD + o];
    wp[idx] = f2bf(v);
}

__global__ __launch_bounds__(128) void kan_mfma(const float* __restrict__ x,
                                                const unsigned short* __restrict__ wp,
                                                float* __restrict__ out) {
    __shared__ uint4 feat[Cc * 4 * FW];
    const int rp = blockIdx.x, b = blockIdx.y, tid = threadIdx.x;
    const int wid = tid >> 6, lane = tid & 63, l15 = lane & 15, ks = lane >> 4;
    const int hrow0 = rp * 2;
    for (int i = tid; i < Cc * 4 * FW; i += 128) {
        int wl = i % FW, cr = i / FW, r = cr & 3, c = cr >> 2;
        int col = wl < Ww ? wl : Ww - 1;
        feat[i] = feat_pack(x[((b * Cc + c) * Hh + hrow0 + r) * Ww + col]);
    }
    __syncthreads();
    f32x4 acc[4][4];
    #pragma unroll
    for (int rt = 0; rt < 4; ++rt)
        #pragma unroll
        for (int ct = 0; ct < 4; ++ct) acc[rt][ct] = (f32x4){0.f, 0.f, 0.f, 0.f};
    auto loadA = [&](int chunk, short8* A) {
        int d = chunk * 4 + ks;
        int c = (d * 57) >> 9;
        int rem = d - c * 9;
        int di = (rem * 11) >> 5;
        int dj = rem - di * 3;
        const short8* ap = (const short8*)&feat[(c * 4 + wid + di) * FW + l15 + dj];
        A[0] = ap[0]; A[1] = ap[16]; A[2] = ap[32]; A[3] = ap[48];
    };
    auto loadB = [&](int chunk, short8* Bf) {
        int d = chunk * 4 + ks;
        const short8* bp = (const short8*)wp + (d * 64 + l15);
        Bf[0] = bp[0]; Bf[1] = bp[16]; Bf[2] = bp[32]; Bf[3] = bp[48];
    };
    short8 A0[4], B0[4], A1[4], B1[4];
    loadA(0, A0); loadB(0, B0);
    for (int cb = 0; cb < NCHUNK; cb += 2) {
        loadA(cb + 1, A1); loadB(cb + 1, B1);
        #pragma unroll
        for (int rt = 0; rt < 4; ++rt)
            #pragma unroll
            for (int ct = 0; ct < 4; ++ct)
                acc[rt][ct] = __builtin_amdgcn_mfma_f32_16x16x32_bf16(A0[rt], B0[ct], acc[rt][ct], 0, 0, 0);
        if (cb + 2 < NCHUNK) { loadA(cb + 2, A0); loadB(cb + 2, B0); }
        #pragma unroll
        for (int rt = 0; rt < 4; ++rt)
            #pragma unroll
            for (int ct = 0; ct < 4; ++ct)
                acc[rt][ct] = __builtin_amdgcn_mfma_f32_16x16x32_bf16(A1[rt], B1[ct], acc[rt][ct], 0, 0, 0);
    }
    __syncthreads();
    float* sC = ((float*)feat) + wid * (OD * FW);
    #pragma unroll
    for (int rt = 0; rt < 4; ++rt)
        #pragma unroll
        for (int ct = 0; ct < 4; ++ct)
            *(f32x4*)&sC[(ct * 16 + l15) * FW + rt * 16 + ks * 4] = acc[rt][ct];
    const int orow = hrow0 + wid;
    for (int j = 0; j < OD; ++j) {
        float v = sC[j * FW + lane];
        if (lane < WO) out[((b * OD + j) * HO + orow) * WO + lane] = v;
    }
}

extern "C" void kernel_launch(void* const* d_in, const int* in_sizes, int n_in,
                              void* d_out, int out_size, void* d_ws, size_t ws_size,
                              hipStream_t stream) {
    (void)in_sizes; (void)n_in; (void)out_size;
    const float* x     = (const float*)d_in[0];
    const float* coef  = (const float*)d_in[1];
    const float* sbase = (const float*)d_in[2];
    const float* ssp   = (const float*)d_in[3];
    float* out = (float*)d_out;

    const size_t wps_bytes   = (size_t)BSM_U16 * 2;                   // 155,648
    const size_t featg_bytes = (size_t)Bsz * Cc * Hh * Ww * 16;       // 33,554,432
    const size_t need = wps_bytes + featg_bytes + 64;

    if (ws_size >= need) {
        unsigned short* wps = (unsigned short*)d_ws;
        uint4* fg = (uint4*)((char*)d_ws + wps_bytes);
        kan_feat<<<1024 + 38, 256, 0, stream>>>(x, coef, sbase, ssp, fg, wps);
        kan_gemm<<<256, 512, 0, stream>>>(fg, wps, out);
    } else if (ws_size >= (size_t)ND * OD * 8 * 2) {
        unsigned short* wp = (unsigned short*)d_ws;
        kan_prep<<<(ND * OD * 8 + 255) / 256, 256, 0, stream>>>(coef, sbase, ssp, wp);
        dim3 grid(HO / 2, Bsz);
        kan_mfma<<<grid, 128, 0, stream>>>(x, wp, out);
    }
}

// Round 5
// 51.382 us; speedup vs baseline: 1.0636x; 1.0636x over previous
//
#include <hip/hip_runtime.h>
#include <math.h>

#define Bsz 32
#define Cc  16
#define Hh  64
#define Ww  64
#define HO  62
#define WO  62
#define OD  64
#define ND  144           // input dims; K-order: slot(cb,ks) holds d = ks*36 + cb
#define NCHUNK 36         // K = 1152 = 36 chunks of 32
#define BSKEW 520         // ushorts per K-slot in skewed B image (1040 B)
#define BSM_U16 77824     // 149.66 slots * 520 = 155,648 B LDS image

using short8 = __attribute__((ext_vector_type(8))) short;
using f32x4  = __attribute__((ext_vector_type(4))) float;

__device__ __forceinline__ unsigned short f2bf(float f) {
    union { float f; unsigned u; } v; v.f = f;
    unsigned r = v.u + 0x7fff + ((v.u >> 16) & 1);
    return (unsigned short)(r >> 16);
}
__device__ __forceinline__ float bf2f(unsigned short h) {
    union { unsigned u; float f; } v; v.u = ((unsigned)h) << 16; return v.f;
}

__device__ __forceinline__ uint4 feat_pack(float xv) {
    float xi = (xv + 3.0f) * 1.5f;
    float fi = floorf(xi);
    int   ii = (int)fi;
    float u  = xi - fi;
    float u2 = u * u, u3 = u2 * u;
    float P0 = u3 * (1.0f / 6.0f);
    float P1 = (1.0f + 3.0f * u + 3.0f * u2 - 3.0f * u3) * (1.0f / 6.0f);
    float P2 = (4.0f - 6.0f * u2 + 3.0f * u3) * (1.0f / 6.0f);
    float om = 1.0f - u;
    float P3 = om * om * om * (1.0f / 6.0f);
    bool ok = (ii >= 0) && (ii <= 8);
    float bas[6];
    #pragma unroll
    for (int n = 0; n < 6; ++n) {
        int t = ii - n;
        float v = (t == 0) ? P0 : (t == 1) ? P1 : (t == 2) ? P2 : (t == 3) ? P3 : 0.0f;
        bas[n] = ok ? v : 0.0f;
    }
    float s = xv / (1.0f + __expf(-xv));
    unsigned short sh = f2bf(s);
    unsigned short sl = f2bf(s - bf2f(sh));
    uint4 pk;
    pk.x = (unsigned)f2bf(bas[0]) | ((unsigned)f2bf(bas[1]) << 16);
    pk.y = (unsigned)f2bf(bas[2]) | ((unsigned)f2bf(bas[3]) << 16);
    pk.z = (unsigned)f2bf(bas[4]) | ((unsigned)f2bf(bas[5]) << 16);
    pk.w = (unsigned)sh | ((unsigned)sl << 16);
    return pk;
}

// ---- kernel 1 (fused): bid<1024 compute features (float4 loads, XCD-affine:
//      bid&7 == batch&7); bid>=1024 pack the K-permuted skewed bf16 weight image ----
__global__ __launch_bounds__(256) void kan_feat(const float* __restrict__ x,
                                                const float* __restrict__ coef,
                                                const float* __restrict__ sbase,
                                                const float* __restrict__ ssp,
                                                uint4* __restrict__ fg,
                                                unsigned short* __restrict__ wps) {
    const int bid = blockIdx.x, tid = threadIdx.x;
    if (bid < 1024) {
        const int bb = bid & 31, part = bid >> 5;         // xcd = bid%8 = bb%8
        #pragma unroll
        for (int p = 0; p < 2; ++p) {
            int e0 = (bb * 32 + part) * 2048 + p * 1024 + tid * 4;
            float4 xv = *(const float4*)&x[e0];
            fg[e0 + 0] = feat_pack(xv.x);
            fg[e0 + 1] = feat_pack(xv.y);
            fg[e0 + 2] = feat_pack(xv.z);
            fg[e0 + 3] = feat_pack(xv.w);
        }
    } else {
        int g = (bid - 1024) * 256 + tid;      // uint4 index, < 9728
        if (g >= BSM_U16 / 8) return;
        int p8   = g * 8;                      // BSKEW=520 divisible by 8: one slot per uint4
        int slot = p8 / BSKEW;
        int o    = (p8 - slot * BSKEW) >> 3;   // 0..64 (64 = tail pad)
        unsigned short v8[8];
        #pragma unroll
        for (int n = 0; n < 8; ++n) v8[n] = 0;
        if (slot < ND && o < 64) {
            int cb = slot >> 2, ks = slot & 3;
            int dsrc = ks * 36 + cb;           // K-order permutation
            float sspv = ssp[dsrc * OD + o];
            #pragma unroll
            for (int n = 0; n < 6; ++n) v8[n] = f2bf(coef[(dsrc * OD + o) * 6 + n] * sspv);
            unsigned short sb = f2bf(sbase[dsrc * OD + o]);
            v8[6] = sb; v8[7] = sb;
        }
        uint4 pk;
        pk.x = (unsigned)v8[0] | ((unsigned)v8[1] << 16);
        pk.y = (unsigned)v8[2] | ((unsigned)v8[3] << 16);
        pk.z = (unsigned)v8[4] | ((unsigned)v8[5] << 16);
        pk.w = (unsigned)v8[6] | ((unsigned)v8[7] << 16);
        *(uint4*)&wps[p8] = pk;
    }
}

// ---- kernel 2: GEMM. B in LDS; wave = one output row; 18-stage branch-free
//      ping-pong (2 chunks/stage); compile-time A/B offsets; direct stores ----
__global__ __launch_bounds__(512) void kan_gemm(const uint4* __restrict__ fg,
                                                const unsigned short* __restrict__ wps,
                                                float* __restrict__ out) {
    __shared__ unsigned short bsm[BSM_U16];   // 155,648 B

    const int tid  = threadIdx.x;
    const int bid  = blockIdx.x;
    const int bb   = bid & 31;                // xcd = bid%8 = bb%8 (matches feat)
    const int hg   = bid >> 5;                // 0..7
    const int wid  = tid >> 6;
    const int h    = hg * 8 + wid;
    const int lane = tid & 63;
    const int l15  = lane & 15;
    const int ks   = lane >> 4;
    const bool alive = (h < HO);

    {   // stage B (global -> LDS)
        const uint4* src = (const uint4*)wps;
        uint4* dst = (uint4*)bsm;
        #pragma unroll
        for (int it = 0; it < 19; ++it) dst[it * 512 + tid] = src[it * 512 + tid];
    }
    __syncthreads();

    f32x4 acc[4][4];
    #pragma unroll
    for (int rt = 0; rt < 4; ++rt)
        #pragma unroll
        for (int ct = 0; ct < 4; ++ct) acc[rt][ct] = (f32x4){0.f, 0.f, 0.f, 0.f};

    if (alive) {
        // A base: d = ks*36 + cb -> c = ks*4 + cb/9 ; (cb/9, di, dj) compile-time
        const short8* awbase = (const short8*)fg +
            (((size_t)(bb * Cc + ks * 4) * 64 + h) << 6) + l15;
        const unsigned short* bbase = bsm + ks * BSKEW + l15 * 8;

        auto loadA = [&](int cb, short8* A) {
            const int cc = cb / 9, rem = cb % 9, di = rem / 3, dj = rem % 3;
            const short8* ap = awbase + ((cc * 64 + di) * 64 + dj);
            A[0] = ap[0]; A[1] = ap[16]; A[2] = ap[32]; A[3] = ap[48];
        };
        auto loadB = [&](int cb, short8* Bf) {
            const short8* bp = (const short8*)(bbase + cb * 4 * BSKEW);
            Bf[0] = bp[0]; Bf[1] = bp[16]; Bf[2] = bp[32]; Bf[3] = bp[48];
        };
        auto mfmas = [&](const short8* Ax, const short8* Bx) {
            #pragma unroll
            for (int rt = 0; rt < 4; ++rt)
                #pragma unroll
                for (int ct = 0; ct < 4; ++ct)
                    acc[rt][ct] = __builtin_amdgcn_mfma_f32_16x16x32_bf16(Ax[rt], Bx[ct], acc[rt][ct], 0, 0, 0);
        };

        short8 Aa[8], Ba[8], Ab[8], Bb[8];
        loadA(0, Aa); loadA(1, Aa + 4); loadB(0, Ba); loadB(1, Ba + 4);

        #pragma unroll
        for (int s = 0; s < 18; ++s) {
            if ((s & 1) == 0) {
                if (s < 17) { loadA(2*s+2, Ab); loadA(2*s+3, Ab+4); loadB(2*s+2, Bb); loadB(2*s+3, Bb+4); }
                mfmas(Aa, Ba); mfmas(Aa + 4, Ba + 4);
            } else {
                if (s < 17) { loadA(2*s+2, Aa); loadA(2*s+3, Aa+4); loadB(2*s+2, Ba); loadB(2*s+3, Ba+4); }
                mfmas(Ab, Bb); mfmas(Ab + 4, Bb + 4);
            }
        }

        // direct stores: lane (l15,ks) holds o = ct*16+l15, w = rt*16+ks*4..+3
        #pragma unroll
        for (int ct = 0; ct < 4; ++ct) {
            const int o = ct * 16 + l15;
            float* orow = out + (((size_t)(bb * OD + o) * HO + h) * WO);
            #pragma unroll
            for (int rt = 0; rt < 4; ++rt) {
                const int w0 = rt * 16 + ks * 4;
                f32x4 v = acc[rt][ct];
                *(float2*)(orow + w0) = (float2){v.x, v.y};
                if (w0 + 2 < WO) *(float2*)(orow + w0 + 2) = (float2){v.z, v.w};
            }
        }
    }
}

// =================== fallback path (no large ws): round-2 kernels ===================
#define FW 68
__global__ __launch_bounds__(256) void kan_prep(const float* __restrict__ coef,
                                                const float* __restrict__ sbase,
                                                const float* __restrict__ ssp,
                                                unsigned short* __restrict__ wp) {
    int idx = blockIdx.x * 256 + threadIdx.x;
    if (idx >= ND * OD * 8) return;
    int n = idx & 7, o = (idx >> 3) & 63, d = idx >> 9;
    float v = (n < 6) ? coef[(d * OD + o) * 6 + n] * ssp[d * OD + o] : sbase[d * OD + o];
    wp[idx] = f2bf(v);
}

__global__ __launch_bounds__(128) void kan_mfma(const float* __restrict__ x,
                                                const unsigned short* __restrict__ wp,
                                                float* __restrict__ out) {
    __shared__ uint4 feat[Cc * 4 * FW];
    const int rp = blockIdx.x, b = blockIdx.y, tid = threadIdx.x;
    const int wid = tid >> 6, lane = tid & 63, l15 = lane & 15, ks = lane >> 4;
    const int hrow0 = rp * 2;
    for (int i = tid; i < Cc * 4 * FW; i += 128) {
        int wl = i % FW, cr = i / FW, r = cr & 3, c = cr >> 2;
        int col = wl < Ww ? wl : Ww - 1;
        feat[i] = feat_pack(x[((b * Cc + c) * Hh + hrow0 + r) * Ww + col]);
    }
    __syncthreads();
    f32x4 acc[4][4];
    #pragma unroll
    for (int rt = 0; rt < 4; ++rt)
        #pragma unroll
        for (int ct = 0; ct < 4; ++ct) acc[rt][ct] = (f32x4){0.f, 0.f, 0.f, 0.f};
    auto loadA = [&](int chunk, short8* A) {
        int d = chunk * 4 + ks;
        int c = (d * 57) >> 9;
        int rem = d - c * 9;
        int di = (rem * 11) >> 5;
        int dj = rem - di * 3;
        const short8* ap = (const short8*)&feat[(c * 4 + wid + di) * FW + l15 + dj];
        A[0] = ap[0]; A[1] = ap[16]; A[2] = ap[32]; A[3] = ap[48];
    };
    auto loadB = [&](int chunk, short8* Bf) {
        int d = chunk * 4 + ks;
        const short8* bp = (const short8*)wp + (d * 64 + l15);
        Bf[0] = bp[0]; Bf[1] = bp[16]; Bf[2] = bp[32]; Bf[3] = bp[48];
    };
    short8 A0[4], B0[4], A1[4], B1[4];
    loadA(0, A0); loadB(0, B0);
    for (int cb = 0; cb < NCHUNK; cb += 2) {
        loadA(cb + 1, A1); loadB(cb + 1, B1);
        #pragma unroll
        for (int rt = 0; rt < 4; ++rt)
            #pragma unroll
            for (int ct = 0; ct < 4; ++ct)
                acc[rt][ct] = __builtin_amdgcn_mfma_f32_16x16x32_bf16(A0[rt], B0[ct], acc[rt][ct], 0, 0, 0);
        if (cb + 2 < NCHUNK) { loadA(cb + 2, A0); loadB(cb + 2, B0); }
        #pragma unroll
        for (int rt = 0; rt < 4; ++rt)
            #pragma unroll
            for (int ct = 0; ct < 4; ++ct)
                acc[rt][ct] = __builtin_amdgcn_mfma_f32_16x16x32_bf16(A1[rt], B1[ct], acc[rt][ct], 0, 0, 0);
    }
    __syncthreads();
    float* sC = ((float*)feat) + wid * (OD * FW);
    #pragma unroll
    for (int rt = 0; rt < 4; ++rt)
        #pragma unroll
        for (int ct = 0; ct < 4; ++ct)
            *(f32x4*)&sC[(ct * 16 + l15) * FW + rt * 16 + ks * 4] = acc[rt][ct];
    const int orow = hrow0 + wid;
    for (int j = 0; j < OD; ++j) {
        float v = sC[j * FW + lane];
        if (lane < WO) out[((b * OD + j) * HO + orow) * WO + lane] = v;
    }
}

extern "C" void kernel_launch(void* const* d_in, const int* in_sizes, int n_in,
                              void* d_out, int out_size, void* d_ws, size_t ws_size,
                              hipStream_t stream) {
    (void)in_sizes; (void)n_in; (void)out_size;
    const float* x     = (const float*)d_in[0];
    const float* coef  = (const float*)d_in[1];
    const float* sbase = (const float*)d_in[2];
    const float* ssp   = (const float*)d_in[3];
    float* out = (float*)d_out;

    const size_t wps_bytes   = (size_t)BSM_U16 * 2;                   // 155,648
    const size_t featg_bytes = (size_t)Bsz * Cc * Hh * Ww * 16;       // 33,554,432
    const size_t need = wps_bytes + featg_bytes + 64;

    if (ws_size >= need) {
        unsigned short* wps = (unsigned short*)d_ws;
        uint4* fg = (uint4*)((char*)d_ws + wps_bytes);
        kan_feat<<<1024 + 38, 256, 0, stream>>>(x, coef, sbase, ssp, fg, wps);
        kan_gemm<<<256, 512, 0, stream>>>(fg, wps, out);
    } else if (ws_size >= (size_t)ND * OD * 8 * 2) {
        unsigned short* wp = (unsigned short*)d_ws;
        kan_prep<<<(ND * OD * 8 + 255) / 256, 256, 0, stream>>>(coef, sbase, ssp, wp);
        dim3 grid(HO / 2, Bsz);
        kan_mfma<<<grid, 128, 0, stream>>>(x, wp, out);
    }
}